// Round 9
// baseline (166.244 us; speedup 1.0000x reference)
//
#include <hip/hip_runtime.h>
#include <cmath>

// SSIM fused kernel for B=16, C=3, H=W=512 fp32 images.
// R9 = R8 resubmitted verbatim (R8 bench was an infra failure: "container
// failed twice" — no counters, theory untested).
// R8 = R2 chassis (H-first, 512 thr, 32x512 stripe, 44-float ring,
// double-buffered float2 LDS rows, 1 barrier/row) + two pipe-neutral cuts.
// Evidence so far: R4 (VALU->LDS trade) lost; R5 (VGPR>128) spilled;
// R6 (VGPR>64) halved residency; R7 (barrier-free) proved barriers cheap
// and kernel VALU-issue-bound (~47us issue + ~18us LDS/VMEM residue).
// R8 changes:
//  - (s,d) transform: stage s=a+b, d=a-b. H-tap chains become
//    {w*s, w*d, w*s^2, w*d^2} = 6 VALU/tap vs 7 (ab cross-product gone);
//    epilogue recovers mu1mu2=(Sum^2-Dif^2)/4, G*ab=(VS2-VD2)/4 (+4 instr).
//    Same LDS bytes, same zero-padding semantics.
//  - depth-2 VMEM prefetch: row i+2 loads issue at iter i. Static reg
//    rotation via 22-deep unroll (i&1 == j&1 at compile time).
// Sentinels: VGPR <= 64 (residency cliff), WRITE_SIZE ~24KB (no spill),
// SQ_LDS_BANK_CONFLICT ~0.

#define IMG_H 512
#define IMG_W 512
#define STRIPE 32
#define NSTR (IMG_H / STRIPE)      // 16
#define NPLANES 48                 // 16*3
#define NBLOCKS (NPLANES * NSTR)   // 768
#define SSIM_C1 (0.01f * 0.01f)
#define SSIM_C2 (0.03f * 0.03f)

typedef float f32x2 __attribute__((ext_vector_type(2)));

struct W2x11 { float2 w[11]; };   // pre-broadcast {w,w} pairs

__launch_bounds__(512, 2)
__global__ void ssim_main(const float* __restrict__ img1,
                          const float* __restrict__ img2,
                          float* __restrict__ blockSums, W2x11 wvp) {
    // slot s holds (sum, diff) of col s-5; cols 0..4 / 517..521 are halo
    __shared__ float2 tb[2][528];
    __shared__ float red[8];

    const int x = threadIdx.x;            // 0..511, one output column
    const int bid = blockIdx.x;
    const int plane = bid >> 4;           // /NSTR
    const int stripe = bid & (NSTR - 1);
    const int y0 = stripe * STRIPE;
    const size_t base = (size_t)plane * (IMG_H * IMG_W);

    // zero halo pads (s=d=0 == a=b=0 == reference zero padding)
    if (x < 10) {
        const int col = (x < 5) ? x : (x + 512);
        tb[0][col] = make_float2(0.f, 0.f);
        tb[1][col] = make_float2(0.f, 0.f);
    }

    // ring of H-filtered (Sum,Dif) and (S2,D2) pairs, static-indexed
    f32x2 rSD[11], rQ[11];
    float acc = 0.f;

    // depth-2 prefetch registers: even-parity rows and odd-parity rows
    float pea = 0.f, peb = 0.f, poa = 0.f, pob = 0.f;
    {
        const int r0 = y0 - 5;            // staged row 0 (even)
        const int r1 = y0 - 4;            // staged row 1 (odd)
        if (r0 >= 0) {
            pea = img1[base + (size_t)r0 * IMG_W + x];
            peb = img2[base + (size_t)r0 * IMG_W + x];
        }
        if (r1 >= 0) {
            poa = img1[base + (size_t)r1 * IMG_W + x];
            pob = img2[base + (size_t)r1 * IMG_W + x];
        }
    }

    int buf = 0;
#pragma unroll 1
    for (int c = 0; c < 2; ++c) {
#pragma unroll
        for (int j = 0; j < 22; ++j) {
            const int i = c * 22 + j;      // staged row 0..43; work for i<42
            if (i < 42) {                  // compile-time per (c,j)
                // consume this row's prefetched pair (parity static in j)
                const float pa = (j & 1) ? poa : pea;
                const float pb = (j & 1) ? pob : peb;
                // stage (sum, diff) into LDS
                tb[buf][x + 5] = make_float2(pa + pb, pa - pb);
                // prefetch row i+2 into the same-parity registers
                {
                    float na = 0.f, nb = 0.f;
                    const int rn = y0 - 3 + i;     // = y0-5 + (i+2)
                    if (i + 2 < 42 && rn >= 0 && rn < IMG_H) {
                        const size_t rb = base + (size_t)rn * IMG_W;
                        na = img1[rb + x];
                        nb = img2[rb + x];
                    }
                    if (j & 1) { poa = na; pob = nb; }
                    else       { pea = na; peb = nb; }
                }
                __syncthreads();
                // horizontal 11-tap conv: 6 VALU/tap
                f32x2 hSD = {0.f, 0.f}, hQ = {0.f, 0.f};
#pragma unroll
                for (int k = 0; k < 11; ++k) {
                    const float2 t = tb[buf][x + k];   // ds_read_b64
                    f32x2 sd; sd.x = t.x; sd.y = t.y;
                    const f32x2 q = sd * sd;           // s^2, d^2
                    f32x2 w2; w2.x = wvp.w[k].x; w2.y = wvp.w[k].y;
                    hSD = __builtin_elementwise_fma(w2, sd, hSD);
                    hQ  = __builtin_elementwise_fma(w2, q,  hQ);
                }
                rSD[j % 11] = hSD;   // i%11 == j%11 (22 = 2*11), static
                rQ [j % 11] = hQ;

                if (i >= 10) {  // output row y = y0 + i - 10
                    f32x2 vSD = {0.f, 0.f}, vQ = {0.f, 0.f};
#pragma unroll
                    for (int k = 0; k < 11; ++k) {
                        const int s = (j + 1 + k) % 11;  // static per (j,k)
                        f32x2 w2; w2.x = wvp.w[k].x; w2.y = wvp.w[k].y;
                        vSD = __builtin_elementwise_fma(w2, rSD[s], vSD);
                        vQ  = __builtin_elementwise_fma(w2, rQ[s],  vQ);
                    }
                    // Sum = mu1+mu2, Dif = mu1-mu2, VS2 = G*(s^2), VD2 = G*(d^2)
                    const float ss = vSD.x * vSD.x;
                    const float dd = vSD.y * vSD.y;
                    const float e1 = (ss - dd) * 0.5f;      // 2*mu1*mu2
                    const float e2 = (ss + dd) * 0.5f;      // mu1^2+mu2^2
                    const float f1 = (vQ.x - vQ.y) * 0.5f;  // 2*G*(ab)
                    const float f2 = (vQ.x + vQ.y) * 0.5f;  // G*(a^2+b^2)
                    const float num = (e1 + SSIM_C1) * ((f1 - e1) + SSIM_C2);
                    const float den = (e2 + SSIM_C1) * ((f2 - e2) + SSIM_C2);
                    acc = fmaf(num, __builtin_amdgcn_rcpf(den), acc);
                }
                buf ^= 1;
            }
        }
    }

    // block reduction: wave shuffle, then 8 wave-sums via LDS
#pragma unroll
    for (int off = 32; off >= 1; off >>= 1)
        acc += __shfl_down(acc, off, 64);
    const int wave = x >> 6, lane = x & 63;
    if (lane == 0) red[wave] = acc;
    __syncthreads();
    if (x == 0) {
        float s = 0.f;
#pragma unroll
        for (int k = 0; k < 8; ++k) s += red[k];
        blockSums[bid] = s;
    }
}

__global__ void ssim_reduce(const float* __restrict__ bs,
                            float* __restrict__ out) {
    __shared__ double red[4];
    const int t = threadIdx.x;  // 256 threads
    double a = 0.0;
    for (int idx = t; idx < NBLOCKS; idx += 256) a += (double)bs[idx];
#pragma unroll
    for (int off = 32; off >= 1; off >>= 1)
        a += __shfl_down(a, off, 64);
    const int wave = t >> 6, lane = t & 63;
    if (lane == 0) red[wave] = a;
    __syncthreads();
    if (t == 0) {
        const double s = red[0] + red[1] + red[2] + red[3];
        out[0] = (float)(s / (double)((double)NPLANES * IMG_H * IMG_W));
    }
}

extern "C" void kernel_launch(void* const* d_in, const int* in_sizes, int n_in,
                              void* d_out, int out_size, void* d_ws, size_t ws_size,
                              hipStream_t stream) {
    const float* img1 = (const float*)d_in[0];
    const float* img2 = (const float*)d_in[1];
    float* out = (float*)d_out;
    float* bs = (float*)d_ws;   // 768 floats of scratch

    // Gaussian weights, faithful to reference: center 5.5, sigma 1.5
    W2x11 wv;
    double g[11], s = 0.0;
    for (int i = 0; i < 11; ++i) {
        const double d = (double)i - 5.5;
        g[i] = exp(-(d * d) / (2.0 * 1.5 * 1.5));
        s += g[i];
    }
    for (int i = 0; i < 11; ++i) {
        const float w = (float)(g[i] / s);
        wv.w[i] = make_float2(w, w);
    }

    ssim_main<<<NBLOCKS, 512, 0, stream>>>(img1, img2, bs, wv);
    ssim_reduce<<<1, 256, 0, stream>>>(bs, out);
}

// Round 10
// 143.160 us; speedup vs baseline: 1.1612x; 1.1612x over previous
//
#include <hip/hip_runtime.h>
#include <cmath>

// SSIM fused kernel for B=16, C=3, H=W=512 fp32 images.
// R10 = (s,d) transform applied to the VERBATIM R2 skeleton.
// R9 post-mortem: the transform never got tested — the 22-deep unroll +
// parity depth-2 prefetch let the scheduler hoist across 22 iterations,
// VGPR 36 -> 128 cap, 4.2 MB spill, 80us. Rule: keep the 11-deep body,
// change only arithmetic inside it (R5/R6/R9 all died on live-range
// expansion).
// Only change vs R2 (64.8us, VGPR 36, VALU 72%, 0 conflicts):
//  - LDS stages (s,d) = (a+b, a-b) instead of (a,b) (+2 VALU/row stage).
//  - H-tap: {fma w*s, fma w*d, q=sd*sd (2 mul), fma w*s2, fma w*d2}
//    = 6 VALU/tap vs R2's 7 (a*b cross-chain gone).
//  - Epilogue recovers 2mu1mu2=(S^2-D^2)/2, mu1^2+mu2^2=(S^2+D^2)/2,
//    2G(ab)=(Q_s-Q_d)/2, G(a^2+b^2)=(Q_s+Q_d)/2 (+4 instr/output).
//  Zero-padding semantics unchanged (s=d=0 <=> a=b=0). Exact same LDS
//  bytes, barriers, prefetch depth, ring size (44 floats).
// Sentinels: VGPR <= 48, WRITE_SIZE ~24KB, SQ_LDS_BANK_CONFLICT ~0.

#define IMG_H 512
#define IMG_W 512
#define STRIPE 32
#define NSTR (IMG_H / STRIPE)      // 16
#define NPLANES 48                 // 16*3
#define NBLOCKS (NPLANES * NSTR)   // 768
#define SSIM_C1 (0.01f * 0.01f)
#define SSIM_C2 (0.03f * 0.03f)

typedef float f32x2 __attribute__((ext_vector_type(2)));

struct W2x11 { float2 w[11]; };   // pre-broadcast {w,w} pairs

__launch_bounds__(512, 2)
__global__ void ssim_main(const float* __restrict__ img1,
                          const float* __restrict__ img2,
                          float* __restrict__ blockSums, W2x11 wvp) {
    // slot s holds (sum, diff) of col s-5; cols 0..4 / 517..521 are halo
    __shared__ float2 tb[2][528];
    __shared__ float red[8];

    const int x = threadIdx.x;            // 0..511, one output column
    const int bid = blockIdx.x;
    const int plane = bid >> 4;           // /NSTR
    const int stripe = bid & (NSTR - 1);
    const int y0 = stripe * STRIPE;
    const size_t base = (size_t)plane * (IMG_H * IMG_W);

    // zero halo pads (s=d=0 == a=b=0 == reference zero padding)
    if (x < 10) {
        const int col = (x < 5) ? x : (x + 512);
        tb[0][col] = make_float2(0.f, 0.f);
        tb[1][col] = make_float2(0.f, 0.f);
    }

    // ring of H-filtered (S,D) and (Qs,Qd) pairs, static-indexed
    f32x2 rSD[11], rQ[11];
    float acc = 0.f;

    // prefetch first row (r = y0-5) — depth-1, exactly as R2
    float pa = 0.f, pb = 0.f;
    {
        const int r0 = y0 - 5;
        if (r0 >= 0) {
            pa = img1[base + (size_t)r0 * IMG_W + x];
            pb = img2[base + (size_t)r0 * IMG_W + x];
        }
    }

    int buf = 0;
#pragma unroll 1
    for (int c = 0; c < 4; ++c) {
#pragma unroll
        for (int j = 0; j < 11; ++j) {
            const int i = c * 11 + j;      // 0..43; only 0..41 do work
            if (i < 42) {                  // block-uniform guard
                // stage (sum, diff) into LDS
                tb[buf][x + 5] = make_float2(pa + pb, pa - pb);
                // prefetch next row (hidden behind barrier + compute)
                pa = 0.f; pb = 0.f;
                const int rn = y0 - 4 + i;
                if (i + 1 < 42 && rn >= 0 && rn < IMG_H) {
                    pa = img1[base + (size_t)rn * IMG_W + x];
                    pb = img2[base + (size_t)rn * IMG_W + x];
                }
                __syncthreads();
                // horizontal 11-tap conv: 6 VALU/tap
                f32x2 hSD = {0.f, 0.f}, hQ = {0.f, 0.f};
#pragma unroll
                for (int k = 0; k < 11; ++k) {
                    const float2 t = tb[buf][x + k];   // ds_read_b64
                    f32x2 sd; sd.x = t.x; sd.y = t.y;
                    const f32x2 q = sd * sd;           // s^2, d^2
                    f32x2 w2; w2.x = wvp.w[k].x; w2.y = wvp.w[k].y;
                    hSD = __builtin_elementwise_fma(w2, sd, hSD);
                    hQ  = __builtin_elementwise_fma(w2, q,  hQ);
                }
                rSD[j] = hSD; rQ[j] = hQ;

                if (i >= 10) {  // uniform; output row y = y0 + i - 10
                    f32x2 vSD = {0.f, 0.f}, vQ = {0.f, 0.f};
#pragma unroll
                    for (int k = 0; k < 11; ++k) {
                        const int s = (j + 1 + k) % 11;  // static per (j,k)
                        f32x2 w2; w2.x = wvp.w[k].x; w2.y = wvp.w[k].y;
                        vSD = __builtin_elementwise_fma(w2, rSD[s], vSD);
                        vQ  = __builtin_elementwise_fma(w2, rQ[s],  vQ);
                    }
                    // S = mu1+mu2, D = mu1-mu2; Qs = G*s^2, Qd = G*d^2
                    const float ss = vSD.x * vSD.x;
                    const float dd = vSD.y * vSD.y;
                    const float e1 = (ss - dd) * 0.5f;      // 2*mu1*mu2
                    const float e2 = (ss + dd) * 0.5f;      // mu1^2+mu2^2
                    const float f1 = (vQ.x - vQ.y) * 0.5f;  // 2*G*(ab)
                    const float f2 = (vQ.x + vQ.y) * 0.5f;  // G*(a^2+b^2)
                    const float num = (e1 + SSIM_C1) * ((f1 - e1) + SSIM_C2);
                    const float den = (e2 + SSIM_C1) * ((f2 - e2) + SSIM_C2);
                    acc = fmaf(num, __builtin_amdgcn_rcpf(den), acc);
                }
                buf ^= 1;
            }
        }
    }

    // block reduction: wave shuffle, then 8 wave-sums via LDS
#pragma unroll
    for (int off = 32; off >= 1; off >>= 1)
        acc += __shfl_down(acc, off, 64);
    const int wave = x >> 6, lane = x & 63;
    if (lane == 0) red[wave] = acc;
    __syncthreads();
    if (x == 0) {
        float s = 0.f;
#pragma unroll
        for (int k = 0; k < 8; ++k) s += red[k];
        blockSums[bid] = s;
    }
}

__global__ void ssim_reduce(const float* __restrict__ bs,
                            float* __restrict__ out) {
    __shared__ double red[4];
    const int t = threadIdx.x;  // 256 threads
    double a = 0.0;
    for (int idx = t; idx < NBLOCKS; idx += 256) a += (double)bs[idx];
#pragma unroll
    for (int off = 32; off >= 1; off >>= 1)
        a += __shfl_down(a, off, 64);
    const int wave = t >> 6, lane = t & 63;
    if (lane == 0) red[wave] = a;
    __syncthreads();
    if (t == 0) {
        const double s = red[0] + red[1] + red[2] + red[3];
        out[0] = (float)(s / (double)((double)NPLANES * IMG_H * IMG_W));
    }
}

extern "C" void kernel_launch(void* const* d_in, const int* in_sizes, int n_in,
                              void* d_out, int out_size, void* d_ws, size_t ws_size,
                              hipStream_t stream) {
    const float* img1 = (const float*)d_in[0];
    const float* img2 = (const float*)d_in[1];
    float* out = (float*)d_out;
    float* bs = (float*)d_ws;   // 768 floats of scratch

    // Gaussian weights, faithful to reference: center 5.5, sigma 1.5
    W2x11 wv;
    double g[11], s = 0.0;
    for (int i = 0; i < 11; ++i) {
        const double d = (double)i - 5.5;
        g[i] = exp(-(d * d) / (2.0 * 1.5 * 1.5));
        s += g[i];
    }
    for (int i = 0; i < 11; ++i) {
        const float w = (float)(g[i] / s);
        wv.w[i] = make_float2(w, w);
    }

    ssim_main<<<NBLOCKS, 512, 0, stream>>>(img1, img2, bs, wv);
    ssim_reduce<<<1, 256, 0, stream>>>(bs, out);
}

// Round 11
// 138.192 us; speedup vs baseline: 1.2030x; 1.0359x over previous
//
#include <hip/hip_runtime.h>
#include <cmath>

// SSIM fused kernel for B=16, C=3, H=W=512 fp32 images.
// R11 = R10 (WIN: 54.2us, VGPR 36, VALU 57.6%, conflicts 0) + depth-2
// VMEM prefetch via explicit register rotation.
// R10 post-mortem: (s,d) transform cut main 64.8->54.2 (every H-tap op
// became packable). Both pipes now ~57% busy -> ~23us of stall. Barriers
// ruled out (R7); grid changes ruled out (R3/R6). Remaining suspect:
// depth-1 prefetch gives the row-load only ~1 iteration of slack vs
// 200-400cy L2/L3 latency, and the vmcnt(0) wait lands at the next stage.
// R9 tested this theory wrongly (22-unroll -> VGPR 128 + 4MB spill).
// R11 does it minimally: (pa,pb)=current row (landed ~2 iters ago),
// (na,nb)=in flight; stage from pa/pb, rotate pa=na, load i+2 into na/nb.
// Body/unroll structure byte-identical to R10 otherwise (+4 VGPR, 4 movs).
// Sentinels: VGPR <= 56, WRITE_SIZE ~24KB, SQ_LDS_BANK_CONFLICT ~0.
// Decision: neutral result falsifies the latency theory -> R10 structure
// is at its floor (phase-lockstep residue).

#define IMG_H 512
#define IMG_W 512
#define STRIPE 32
#define NSTR (IMG_H / STRIPE)      // 16
#define NPLANES 48                 // 16*3
#define NBLOCKS (NPLANES * NSTR)   // 768
#define SSIM_C1 (0.01f * 0.01f)
#define SSIM_C2 (0.03f * 0.03f)

typedef float f32x2 __attribute__((ext_vector_type(2)));

struct W2x11 { float2 w[11]; };   // pre-broadcast {w,w} pairs

__launch_bounds__(512, 2)
__global__ void ssim_main(const float* __restrict__ img1,
                          const float* __restrict__ img2,
                          float* __restrict__ blockSums, W2x11 wvp) {
    // slot s holds (sum, diff) of col s-5; cols 0..4 / 517..521 are halo
    __shared__ float2 tb[2][528];
    __shared__ float red[8];

    const int x = threadIdx.x;            // 0..511, one output column
    const int bid = blockIdx.x;
    const int plane = bid >> 4;           // /NSTR
    const int stripe = bid & (NSTR - 1);
    const int y0 = stripe * STRIPE;
    const size_t base = (size_t)plane * (IMG_H * IMG_W);

    // zero halo pads (s=d=0 == a=b=0 == reference zero padding)
    if (x < 10) {
        const int col = (x < 5) ? x : (x + 512);
        tb[0][col] = make_float2(0.f, 0.f);
        tb[1][col] = make_float2(0.f, 0.f);
    }

    // ring of H-filtered (S,D) and (Qs,Qd) pairs, static-indexed
    f32x2 rSD[11], rQ[11];
    float acc = 0.f;

    // depth-2 prefetch: (pa,pb) = staged row i (already landed),
    // (na,nb) = staged row i+1 (in flight)
    float pa = 0.f, pb = 0.f, na = 0.f, nb = 0.f;
    {
        const int r0 = y0 - 5;            // staged row 0
        const int r1 = y0 - 4;            // staged row 1
        if (r0 >= 0) {
            pa = img1[base + (size_t)r0 * IMG_W + x];
            pb = img2[base + (size_t)r0 * IMG_W + x];
        }
        if (r1 >= 0) {
            na = img1[base + (size_t)r1 * IMG_W + x];
            nb = img2[base + (size_t)r1 * IMG_W + x];
        }
    }

    int buf = 0;
#pragma unroll 1
    for (int c = 0; c < 4; ++c) {
#pragma unroll
        for (int j = 0; j < 11; ++j) {
            const int i = c * 11 + j;      // 0..43; only 0..41 do work
            if (i < 42) {                  // block-uniform guard
                // stage (sum, diff) into LDS — pa/pb landed ~2 iters ago
                tb[buf][x + 5] = make_float2(pa + pb, pa - pb);
                // rotate: current <- in-flight (waits on load from iter i-1)
                pa = na; pb = nb;
                // issue load of staged row i+2 (consumed at iter i+2)
                na = 0.f; nb = 0.f;
                const int rn = y0 - 3 + i;     // = y0-5 + (i+2)
                if (i + 2 < 42 && rn >= 0 && rn < IMG_H) {
                    const size_t rb = base + (size_t)rn * IMG_W;
                    na = img1[rb + x];
                    nb = img2[rb + x];
                }
                __syncthreads();
                // horizontal 11-tap conv: 3 packed VALU/tap
                f32x2 hSD = {0.f, 0.f}, hQ = {0.f, 0.f};
#pragma unroll
                for (int k = 0; k < 11; ++k) {
                    const float2 t = tb[buf][x + k];   // ds_read_b64
                    f32x2 sd; sd.x = t.x; sd.y = t.y;
                    const f32x2 q = sd * sd;           // s^2, d^2 (pk_mul)
                    f32x2 w2; w2.x = wvp.w[k].x; w2.y = wvp.w[k].y;
                    hSD = __builtin_elementwise_fma(w2, sd, hSD);
                    hQ  = __builtin_elementwise_fma(w2, q,  hQ);
                }
                rSD[j] = hSD; rQ[j] = hQ;

                if (i >= 10) {  // uniform; output row y = y0 + i - 10
                    f32x2 vSD = {0.f, 0.f}, vQ = {0.f, 0.f};
#pragma unroll
                    for (int k = 0; k < 11; ++k) {
                        const int s = (j + 1 + k) % 11;  // static per (j,k)
                        f32x2 w2; w2.x = wvp.w[k].x; w2.y = wvp.w[k].y;
                        vSD = __builtin_elementwise_fma(w2, rSD[s], vSD);
                        vQ  = __builtin_elementwise_fma(w2, rQ[s],  vQ);
                    }
                    // S = mu1+mu2, D = mu1-mu2; Qs = G*s^2, Qd = G*d^2
                    const float ss = vSD.x * vSD.x;
                    const float dd = vSD.y * vSD.y;
                    const float e1 = (ss - dd) * 0.5f;      // 2*mu1*mu2
                    const float e2 = (ss + dd) * 0.5f;      // mu1^2+mu2^2
                    const float f1 = (vQ.x - vQ.y) * 0.5f;  // 2*G*(ab)
                    const float f2 = (vQ.x + vQ.y) * 0.5f;  // G*(a^2+b^2)
                    const float num = (e1 + SSIM_C1) * ((f1 - e1) + SSIM_C2);
                    const float den = (e2 + SSIM_C1) * ((f2 - e2) + SSIM_C2);
                    acc = fmaf(num, __builtin_amdgcn_rcpf(den), acc);
                }
                buf ^= 1;
            }
        }
    }

    // block reduction: wave shuffle, then 8 wave-sums via LDS
#pragma unroll
    for (int off = 32; off >= 1; off >>= 1)
        acc += __shfl_down(acc, off, 64);
    const int wave = x >> 6, lane = x & 63;
    if (lane == 0) red[wave] = acc;
    __syncthreads();
    if (x == 0) {
        float s = 0.f;
#pragma unroll
        for (int k = 0; k < 8; ++k) s += red[k];
        blockSums[bid] = s;
    }
}

__global__ void ssim_reduce(const float* __restrict__ bs,
                            float* __restrict__ out) {
    __shared__ double red[4];
    const int t = threadIdx.x;  // 256 threads
    double a = 0.0;
    for (int idx = t; idx < NBLOCKS; idx += 256) a += (double)bs[idx];
#pragma unroll
    for (int off = 32; off >= 1; off >>= 1)
        a += __shfl_down(a, off, 64);
    const int wave = t >> 6, lane = t & 63;
    if (lane == 0) red[wave] = a;
    __syncthreads();
    if (t == 0) {
        const double s = red[0] + red[1] + red[2] + red[3];
        out[0] = (float)(s / (double)((double)NPLANES * IMG_H * IMG_W));
    }
}

extern "C" void kernel_launch(void* const* d_in, const int* in_sizes, int n_in,
                              void* d_out, int out_size, void* d_ws, size_t ws_size,
                              hipStream_t stream) {
    const float* img1 = (const float*)d_in[0];
    const float* img2 = (const float*)d_in[1];
    float* out = (float*)d_out;
    float* bs = (float*)d_ws;   // 768 floats of scratch

    // Gaussian weights, faithful to reference: center 5.5, sigma 1.5
    W2x11 wv;
    double g[11], s = 0.0;
    for (int i = 0; i < 11; ++i) {
        const double d = (double)i - 5.5;
        g[i] = exp(-(d * d) / (2.0 * 1.5 * 1.5));
        s += g[i];
    }
    for (int i = 0; i < 11; ++i) {
        const float w = (float)(g[i] / s);
        wv.w[i] = make_float2(w, w);
    }

    ssim_main<<<NBLOCKS, 512, 0, stream>>>(img1, img2, bs, wv);
    ssim_reduce<<<1, 256, 0, stream>>>(bs, out);
}